// Round 6
// baseline (4331.754 us; speedup 1.0000x reference)
//
#include <hip/hip_runtime.h>
#include <hip/hip_bf16.h>

// CLIP ViT-B/16 visual forward — Round 5: split-K GEMMs (atomic f32 combine)
// to fix 1-block/CU co-residency starvation on fc2/out-proj; 2-buffer 32KB
// LDS GEMM body (5 blocks/CU capacity).

#define LAYERS 12
#define DMODEL 768
#define NHEADS 12
#define DHEAD  64
#define FFDIM  3072
#define BATCH  32
#define SEQ    197
#define NPATCH 196
#define OUTD   512
#define MROWS  (BATCH * SEQ)   // 6304
#define MPAD   6400            // 50 * 128
#define SPAD   208             // 13 * 16 (padded seq)
#define VSTR   208

typedef __attribute__((ext_vector_type(4))) float f32x4;
typedef __attribute__((ext_vector_type(8))) short bf16x8;

enum { M_F32 = 0, M_ATOM = 1, M_GELU = 2, M_PATCH = 3, M_QKVB = 4 };

__device__ __forceinline__ float b2f(short s) {
    unsigned u = ((unsigned)(unsigned short)s) << 16;
    return __builtin_bit_cast(float, u);
}
__device__ __forceinline__ short f2b(float f) {
    __hip_bfloat16 h = __float2bfloat16(f);
    return __builtin_bit_cast(short, h);
}

__device__ __forceinline__ void gl2lds16(const void* g, void* l) {
    __builtin_amdgcn_global_load_lds(
        (const __attribute__((address_space(1))) void*)g,
        (__attribute__((address_space(3))) void*)l, 16, 0, 0);
}

// ---------------------------------------------------------------- weight cvt
__global__ __launch_bounds__(256) void cvt_bf16_kernel(
    const float* __restrict__ src, __hip_bfloat16* __restrict__ dst, long n)
{
    long i0 = ((long)blockIdx.x * 256 + threadIdx.x) * 4;
    long stride = (long)gridDim.x * 1024;
    for (long i = i0; i < n; i += stride) {
        float4 v = *reinterpret_cast<const float4*>(&src[i]);
        dst[i + 0] = __float2bfloat16(v.x);
        dst[i + 1] = __float2bfloat16(v.y);
        dst[i + 2] = __float2bfloat16(v.z);
        dst[i + 3] = __float2bfloat16(v.w);
    }
}

// ---------------------------------------------------------------- im2col
__global__ __launch_bounds__(256) void im2col_kernel(
    const float* __restrict__ x_inp, __hip_bfloat16* __restrict__ patches)
{
    int bp = blockIdx.x;                 // b*196 + p
    int b = bp / NPATCH, p = bp % NPATCH;
    int py = p / 14, px = p % 14;
    const float* xb = x_inp + (long)b * 3 * 224 * 224;
    for (int e = threadIdx.x; e < 768; e += 256) {
        int c = e >> 8, i = (e >> 4) & 15, j = e & 15;
        patches[(long)bp * 768 + e] =
            __float2bfloat16(xb[((long)c * 224 + py * 16 + i) * 224 + px * 16 + j]);
    }
}

__global__ __launch_bounds__(256) void cls_token_kernel(
    const float* __restrict__ cls_emb, const float* __restrict__ pos_emb,
    float* __restrict__ x)
{
    int b = blockIdx.x;
    for (int d = threadIdx.x; d < DMODEL; d += 256)
        x[(long)b * SEQ * DMODEL + d] = cls_emb[d] + pos_emb[d];
}

// ---------------------------------------------------------------- layernorm
template<int OB>
__global__ __launch_bounds__(256) void ln_kernel(
    const float* __restrict__ in, void* __restrict__ out,
    const float* __restrict__ w, const float* __restrict__ bb,
    long in_stride, long out_stride)
{
    int row = blockIdx.x;
    const float* xr = in + (long)row * in_stride;
    int t = threadIdx.x;
    int lane = t & 63, wid = t >> 6;
    __shared__ float red[8];

    float v[3];
    float s = 0.f;
    #pragma unroll
    for (int i = 0; i < 3; ++i) { v[i] = xr[t + i * 256]; s += v[i]; }
    #pragma unroll
    for (int off = 32; off; off >>= 1) s += __shfl_xor(s, off);
    if (lane == 0) red[wid] = s;
    __syncthreads();
    float mean = (red[0] + red[1] + red[2] + red[3]) * (1.0f / DMODEL);
    float sq = 0.f;
    #pragma unroll
    for (int i = 0; i < 3; ++i) { float d = v[i] - mean; sq += d * d; }
    #pragma unroll
    for (int off = 32; off; off >>= 1) sq += __shfl_xor(sq, off);
    if (lane == 0) red[4 + wid] = sq;
    __syncthreads();
    float rstd = rsqrtf((red[4] + red[5] + red[6] + red[7]) * (1.0f / DMODEL) + 1e-5f);
    #pragma unroll
    for (int i = 0; i < 3; ++i) {
        int d = t + i * 256;
        float o = (v[i] - mean) * rstd * w[d] + bb[d];
        if (OB) ((__hip_bfloat16*)out)[(long)row * out_stride + d] = __float2bfloat16(o);
        else    ((float*)out)[(long)row * out_stride + d] = o;
    }
}

// ---------------------------------------------------------------- bf16 GEMM
// C[M,N] = A[M,K] @ W[N,K]^T (+bias / epilogue per MODE), optional split-K.
// 128x128 tile, BK=32, 2-buffer LDS (32KB -> 5 blocks/CU), prefetch-next then
// one barrier per K-step; bijective XCD-chunked 1D grid swizzle.
// LDS chunk swizzle: c ^= (row>>1)&3 (2-way max on ds_read_b128).
template<int MODE, int SPLITS>
__global__ __launch_bounds__(256) void gemm_bf16(
    const __hip_bfloat16* __restrict__ A, const __hip_bfloat16* __restrict__ W,
    const float* __restrict__ bias, float* __restrict__ Cf,
    __hip_bfloat16* __restrict__ Cb, int M, int N, int K, int NB,
    const float* __restrict__ pos)
{
    __shared__ short As[2][128 * 32];
    __shared__ short Bs[2][128 * 32];
    int tid = threadIdx.x, lane = tid & 63, wv = tid >> 6;

    // bijective XCD-chunked remap (m204)
    int nwg = gridDim.x, bid = blockIdx.x;
    int qq = nwg >> 3, rr = nwg & 7;
    int xcd = bid & 7, idx = bid >> 3;
    int newid = (xcd < rr ? xcd * (qq + 1) : rr * (qq + 1) + (xcd - rr) * qq) + idx;

    int GM = (M + 127) >> 7;
    int per = GM * NB;
    int sK = newid / per;                 // split-K chunk index
    int rem = newid - sK * per;
    int bm = (rem / NB) * 128, bn = (rem % NB) * 128;
    int kchunk = K / SPLITS;
    int k0 = sK * kchunk;

    int wr = wv >> 1, wc = wv & 1;
    f32x4 acc[4][4] = {};

    // staging: thread t -> storage slot (row sr = t/4, chunk sc = t%4);
    // storage chunk sc holds logical chunk sc ^ ((sr>>1)&3).
    int sr = tid >> 2, sc = tid & 3;
    int c_log = sc ^ ((sr >> 1) & 3);
    const short* Ag  = (const short*)A + (long)(bm + sr) * K + k0 + (c_log << 3);
    const short* Bg  = (const short*)W + (long)(bn + sr) * K + k0 + (c_log << 3);
    const short* Ag2 = Ag + (long)64 * K;   // (sr+64) keeps same (sr>>1)&3
    const short* Bg2 = Bg + (long)64 * K;

    // MFMA fragment read offsets (elements)
    int lg = lane >> 4, lr16 = lane & 15;
    int aoff[4], boff[4];
    #pragma unroll
    for (int i = 0; i < 4; ++i) {
        int ra = wr * 64 + i * 16 + lr16;
        aoff[i] = (ra << 5) + ((lg ^ ((ra >> 1) & 3)) << 3);
        int rb = wc * 64 + i * 16 + lr16;
        boff[i] = (rb << 5) + ((lg ^ ((rb >> 1) & 3)) << 3);
    }

    const int KT = kchunk >> 5;
    // prologue: stage tile 0 into buf 0
    gl2lds16(Ag,  (char*)&As[0][0] + tid * 16);
    gl2lds16(Ag2, (char*)&As[0][0] + 4096 + tid * 16);
    gl2lds16(Bg,  (char*)&Bs[0][0] + tid * 16);
    gl2lds16(Bg2, (char*)&Bs[0][0] + 4096 + tid * 16);
    __syncthreads();

    int cur = 0;
    for (int t = 0; t < KT; ++t) {
        if (t + 1 < KT) {
            int ktn = (t + 1) << 5;
            char* Ad = (char*)&As[cur ^ 1][0];
            char* Bd = (char*)&Bs[cur ^ 1][0];
            gl2lds16(Ag + ktn,  Ad + tid * 16);
            gl2lds16(Ag2 + ktn, Ad + 4096 + tid * 16);
            gl2lds16(Bg + ktn,  Bd + tid * 16);
            gl2lds16(Bg2 + ktn, Bd + 4096 + tid * 16);
        }
        const short* Ab = &As[cur][0];
        const short* Bb = &Bs[cur][0];
        bf16x8 af[4], bfr[4];
        #pragma unroll
        for (int i = 0; i < 4; ++i) af[i]  = *reinterpret_cast<const bf16x8*>(&Ab[aoff[i]]);
        #pragma unroll
        for (int i = 0; i < 4; ++i) bfr[i] = *reinterpret_cast<const bf16x8*>(&Bb[boff[i]]);
        #pragma unroll
        for (int mi = 0; mi < 4; ++mi)
            #pragma unroll
            for (int ni = 0; ni < 4; ++ni)
                acc[mi][ni] = __builtin_amdgcn_mfma_f32_16x16x32_bf16(
                    af[mi], bfr[ni], acc[mi][ni], 0, 0, 0);
        __syncthreads();
        cur ^= 1;
    }

    #pragma unroll
    for (int mi = 0; mi < 4; ++mi) {
        int row0 = bm + wr * 64 + mi * 16 + (lane >> 4) * 4;
        #pragma unroll
        for (int ni = 0; ni < 4; ++ni) {
            int col = bn + wc * 64 + ni * 16 + (lane & 15);
            #pragma unroll
            for (int r = 0; r < 4; ++r) {
                int row = row0 + r;
                if (row >= M) continue;
                float v = acc[mi][ni][r];
                if (MODE == M_PATCH) {
                    int pb = row / 196, pp = row - pb * 196;
                    Cf[((long)(pb * SEQ + 1 + pp)) * DMODEL + col] =
                        v + pos[(long)(1 + pp) * DMODEL + col];
                } else if (MODE == M_ATOM) {
                    if (sK == 0) v += bias[col];
                    atomicAdd(&Cf[(long)row * N + col], v);
                } else {
                    v += bias[col];
                    long idx2 = (long)row * N + col;
                    if (MODE == M_F32)      Cf[idx2] = v;
                    else if (MODE == M_QKVB) Cb[idx2] = __float2bfloat16(v);
                    else if (MODE == M_GELU)
                        Cb[idx2] = __float2bfloat16(v / (1.f + __expf(-1.702f * v)));
                }
            }
        }
    }
}

// ---------------------------------------------------------------- attention
// Fused MFMA attention: one block (256 thr, 4 waves) per (b,h).
__global__ __launch_bounds__(256) void attn_kernel(
    const __hip_bfloat16* __restrict__ qkv,  // [MPAD, 2304] bf16
    __hip_bfloat16* __restrict__ o)          // [MPAD, 768]
{
    int bh = blockIdx.x;
    int b = bh / NHEADS, h = bh % NHEADS;
    int tid = threadIdx.x, lane = tid & 63, wv = tid >> 6;
    __shared__ short Ks[SPAD * 64];
    __shared__ short Vt[64 * VSTR];
    __shared__ short Ps[4][16 * VSTR];
    const short* base = (const short*)qkv + (long)b * SEQ * 2304;

    for (int idx = tid; idx < SPAD * 8; idx += 256) {
        int r = idx >> 3, c = idx & 7;
        int4 val = make_int4(0, 0, 0, 0);
        if (r < SEQ)
            val = *reinterpret_cast<const int4*>(base + (long)r * 2304 + 768 + h * 64 + c * 8);
        *reinterpret_cast<int4*>(&Ks[r * 64 + ((c ^ (r & 7)) << 3)]) = val;
    }
    for (int idx = tid; idx < SPAD * 64; idx += 256) {
        int k = idx >> 6, d = idx & 63;
        short v = (k < SEQ) ? base[(long)k * 2304 + 1536 + h * 64 + d] : (short)0;
        Vt[d * VSTR + k] = v;
    }
    __syncthreads();

    int lg = lane >> 4, lr = lane & 15;
    short* Pw = Ps[wv];

    for (int ch = wv; ch < 13; ch += 4) {
        int q0 = ch * 16;
        const short* qp = (const short*)qkv +
            ((long)(b * SEQ) + q0 + lr) * 2304 + h * 64 + (lg << 3);
        bf16x8 qa = *reinterpret_cast<const bf16x8*>(qp);
        bf16x8 qb = *reinterpret_cast<const bf16x8*>(qp + 32);

        f32x4 sc[13];
        #pragma unroll
        for (int f = 0; f < 13; ++f) sc[f] = (f32x4){0.f, 0.f, 0.f, 0.f};
        #pragma unroll
        for (int f = 0; f < 13; ++f) {
            int row = f * 16 + lr;
            int sw = row & 7;
            const short* kr = &Ks[row * 64];
            bf16x8 k0 = *reinterpret_cast<const bf16x8*>(&kr[((lg + 0) ^ sw) << 3]);
            bf16x8 k1 = *reinterpret_cast<const bf16x8*>(&kr[((lg + 4) ^ sw) << 3]);
            sc[f] = __builtin_amdgcn_mfma_f32_16x16x32_bf16(qa, k0, sc[f], 0, 0, 0);
            sc[f] = __builtin_amdgcn_mfma_f32_16x16x32_bf16(qb, k1, sc[f], 0, 0, 0);
        }

        float mrow[4] = {-1e30f, -1e30f, -1e30f, -1e30f};
        #pragma unroll
        for (int f = 0; f < 13; ++f) {
            bool ok = f * 16 + lr < SEQ;
            #pragma unroll
            for (int r = 0; r < 4; ++r)
                if (ok) mrow[r] = fmaxf(mrow[r], sc[f][r] * 0.125f);
        }
        #pragma unroll
        for (int r = 0; r < 4; ++r)
            #pragma unroll
            for (int off = 8; off; off >>= 1)
                mrow[r] = fmaxf(mrow[r], __shfl_xor(mrow[r], off));
        float esum[4] = {0.f, 0.f, 0.f, 0.f};
        #pragma unroll
        for (int f = 0; f < 13; ++f) {
            bool ok = f * 16 + lr < SEQ;
            #pragma unroll
            for (int r = 0; r < 4; ++r) {
                float e = ok ? __expf(sc[f][r] * 0.125f - mrow[r]) : 0.f;
                sc[f][r] = e;
                esum[r] += e;
            }
        }
        #pragma unroll
        for (int r = 0; r < 4; ++r)
            #pragma unroll
            for (int off = 8; off; off >>= 1)
                esum[r] += __shfl_xor(esum[r], off);
        float inv[4];
        #pragma unroll
        for (int r = 0; r < 4; ++r) inv[r] = 1.0f / esum[r];

        #pragma unroll
        for (int f = 0; f < 13; ++f)
            #pragma unroll
            for (int r = 0; r < 4; ++r)
                Pw[(lg * 4 + r) * VSTR + f * 16 + lr] = f2b(sc[f][r] * inv[r]);

        f32x4 oa[4] = {};
        #pragma unroll
        for (int ks = 0; ks < 7; ++ks) {
            int kb = ks * 32 + (lg << 3);
            bf16x8 pa = {};
            if (kb < SPAD) pa = *reinterpret_cast<const bf16x8*>(&Pw[lr * VSTR + kb]);
            #pragma unroll
            for (int d = 0; d < 4; ++d) {
                bf16x8 vb = {};
                if (kb < SPAD)
                    vb = *reinterpret_cast<const bf16x8*>(&Vt[(d * 16 + lr) * VSTR + kb]);
                oa[d] = __builtin_amdgcn_mfma_f32_16x16x32_bf16(pa, vb, oa[d], 0, 0, 0);
            }
        }

        #pragma unroll
        for (int d = 0; d < 4; ++d)
            #pragma unroll
            for (int r = 0; r < 4; ++r) {
                int q = q0 + lg * 4 + r;
                if (q < SEQ)
                    o[((long)(b * SEQ + q)) * DMODEL + h * 64 + d * 16 + lr] =
                        __float2bfloat16(oa[d][r]);
            }
    }
}

// ---------------------------------------------------------------- final proj
__global__ __launch_bounds__(256) void proj_kernel(
    const float* __restrict__ cls_ln,  // [32,768]
    const float* __restrict__ proj,    // [768,512]
    float* __restrict__ out)           // [32,512]
{
    int idx = blockIdx.x * 256 + threadIdx.x;
    int m = idx >> 9, n = idx & 511;
    float s = 0.f;
    #pragma unroll 8
    for (int k = 0; k < 768; ++k)
        s += cls_ln[m * 768 + k] * proj[k * 512 + n];
    out[idx] = s;
}

// ---------------------------------------------------------------- launcher
extern "C" void kernel_launch(void* const* d_in, const int* in_sizes, int n_in,
                              void* d_out, int out_size, void* d_ws, size_t ws_size,
                              hipStream_t stream) {
    const float* x_inp    = (const float*)d_in[0];
    const float* conv_w   = (const float*)d_in[1];
    const float* cls_emb  = (const float*)d_in[2];
    const float* pos_emb  = (const float*)d_in[3];
    const float* ln_pre_w = (const float*)d_in[4];
    const float* ln_pre_b = (const float*)d_in[5];
    const float* ln1_w    = (const float*)d_in[6];
    const float* ln1_b    = (const float*)d_in[7];
    const float* qkv_w    = (const float*)d_in[8];
    const float* qkv_b    = (const float*)d_in[9];
    const float* out_w    = (const float*)d_in[10];
    const float* out_b    = (const float*)d_in[11];
    const float* ln2_w    = (const float*)d_in[12];
    const float* ln2_b    = (const float*)d_in[13];
    const float* fc1_w    = (const float*)d_in[14];
    const float* fc1_b    = (const float*)d_in[15];
    const float* fc2_w    = (const float*)d_in[16];
    const float* fc2_b    = (const float*)d_in[17];
    const float* ln_post_w= (const float*)d_in[18];
    const float* ln_post_b= (const float*)d_in[19];
    const float* proj     = (const float*)d_in[20];

    char* w = (char*)d_ws;
    __hip_bfloat16* wqkv = (__hip_bfloat16*)w; w += (size_t)LAYERS * 2304 * DMODEL * 2;
    __hip_bfloat16* wout = (__hip_bfloat16*)w; w += (size_t)LAYERS * DMODEL * DMODEL * 2;
    __hip_bfloat16* wfc1 = (__hip_bfloat16*)w; w += (size_t)LAYERS * FFDIM * DMODEL * 2;
    __hip_bfloat16* wfc2 = (__hip_bfloat16*)w; w += (size_t)LAYERS * DMODEL * FFDIM * 2;
    __hip_bfloat16* wconv= (__hip_bfloat16*)w; w += (size_t)DMODEL * DMODEL * 2;
    float* x             = (float*)w;          w += (size_t)MROWS * DMODEL * 4;
    __hip_bfloat16* y    = (__hip_bfloat16*)w; w += (size_t)MPAD * DMODEL * 2;
    __hip_bfloat16* qkvb = (__hip_bfloat16*)w; w += (size_t)MPAD * 2304 * 2;
    __hip_bfloat16* attno= (__hip_bfloat16*)w; w += (size_t)MPAD * DMODEL * 2;
    __hip_bfloat16* h1   = (__hip_bfloat16*)w; w += (size_t)MPAD * FFDIM * 2;
    __hip_bfloat16* patches = (__hip_bfloat16*)w; w += (size_t)NPATCH * BATCH * DMODEL * 2;
    float* clsb          = (float*)w;          w += (size_t)BATCH * DMODEL * 4;

    cvt_bf16_kernel<<<2048, 256, 0, stream>>>(qkv_w, wqkv, (long)LAYERS * 2304 * DMODEL);
    cvt_bf16_kernel<<<2048, 256, 0, stream>>>(out_w, wout, (long)LAYERS * DMODEL * DMODEL);
    cvt_bf16_kernel<<<2048, 256, 0, stream>>>(fc1_w, wfc1, (long)LAYERS * FFDIM * DMODEL);
    cvt_bf16_kernel<<<2048, 256, 0, stream>>>(fc2_w, wfc2, (long)LAYERS * DMODEL * FFDIM);
    cvt_bf16_kernel<<<512, 256, 0, stream>>>(conv_w, wconv, (long)DMODEL * DMODEL);

    im2col_kernel<<<NPATCH * BATCH, 256, 0, stream>>>(x_inp, patches);
    gemm_bf16<M_PATCH, 1><<<49 * 6, 256, 0, stream>>>(
        patches, wconv, nullptr, x, nullptr, NPATCH * BATCH, DMODEL, DMODEL, 6, pos_emb);
    cls_token_kernel<<<BATCH, 256, 0, stream>>>(cls_emb, pos_emb, x);
    ln_kernel<0><<<MROWS, 256, 0, stream>>>(x, x, ln_pre_w, ln_pre_b, DMODEL, DMODEL);

    for (int l = 0; l < LAYERS; ++l) {
        ln_kernel<1><<<MROWS, 256, 0, stream>>>(x, y, ln1_w + l * DMODEL, ln1_b + l * DMODEL,
                                                DMODEL, DMODEL);
        gemm_bf16<M_QKVB, 1><<<50 * 18, 256, 0, stream>>>(
            y, wqkv + (long)l * 2304 * DMODEL, qkv_b + (long)l * 2304, nullptr, qkvb,
            MROWS, 2304, DMODEL, 18, nullptr);
        attn_kernel<<<BATCH * NHEADS, 256, 0, stream>>>(qkvb, attno);
        gemm_bf16<M_ATOM, 2><<<50 * 6 * 2, 256, 0, stream>>>(
            attno, wout + (long)l * DMODEL * DMODEL, out_b + (long)l * DMODEL, x, nullptr,
            MROWS, DMODEL, DMODEL, 6, nullptr);
        ln_kernel<1><<<MROWS, 256, 0, stream>>>(x, y, ln2_w + l * DMODEL, ln2_b + l * DMODEL,
                                                DMODEL, DMODEL);
        gemm_bf16<M_GELU, 1><<<50 * 24, 256, 0, stream>>>(
            y, wfc1 + (long)l * FFDIM * DMODEL, fc1_b + (long)l * FFDIM, nullptr, h1,
            MROWS, FFDIM, DMODEL, 24, nullptr);
        gemm_bf16<M_ATOM, 4><<<50 * 6 * 4, 256, 0, stream>>>(
            h1, wfc2 + (long)l * DMODEL * FFDIM, fc2_b + (long)l * DMODEL, x, nullptr,
            MROWS, DMODEL, FFDIM, 6, nullptr);
    }

    ln_kernel<0><<<BATCH, 256, 0, stream>>>(x, clsb, ln_post_w, ln_post_b,
                                            (long)SEQ * DMODEL, DMODEL);
    proj_kernel<<<(BATCH * OUTD) / 256, 256, 0, stream>>>(clsb, proj, (float*)d_out);
}

// Round 7
// 3546.835 us; speedup vs baseline: 1.2213x; 1.2213x over previous
//
#include <hip/hip_runtime.h>
#include <hip/hip_bf16.h>

// CLIP ViT-B/16 visual forward — Round 6: variable M-tile GEMM (TM=64 for
// small-grid GEMMs -> 2.3 blocks/CU co-residency; TM=128 for qkv/fc1).
// No split-K, no atomics. 2-buffer 24-32KB LDS, XCD-chunked swizzle.

#define LAYERS 12
#define DMODEL 768
#define NHEADS 12
#define DHEAD  64
#define FFDIM  3072
#define BATCH  32
#define SEQ    197
#define NPATCH 196
#define OUTD   512
#define MROWS  (BATCH * SEQ)   // 6304
#define MPAD   6400            // 50 * 128
#define SPAD   208             // 13 * 16 (padded seq)
#define VSTR   208

typedef __attribute__((ext_vector_type(4))) float f32x4;
typedef __attribute__((ext_vector_type(8))) short bf16x8;

enum { M_F32 = 0, M_ACC = 1, M_GELU = 2, M_PATCH = 3, M_QKVB = 4 };

__device__ __forceinline__ float b2f(short s) {
    unsigned u = ((unsigned)(unsigned short)s) << 16;
    return __builtin_bit_cast(float, u);
}
__device__ __forceinline__ short f2b(float f) {
    __hip_bfloat16 h = __float2bfloat16(f);
    return __builtin_bit_cast(short, h);
}

__device__ __forceinline__ void gl2lds16(const void* g, void* l) {
    __builtin_amdgcn_global_load_lds(
        (const __attribute__((address_space(1))) void*)g,
        (__attribute__((address_space(3))) void*)l, 16, 0, 0);
}

// ---------------------------------------------------------------- weight cvt
__global__ __launch_bounds__(256) void cvt_bf16_kernel(
    const float* __restrict__ src, __hip_bfloat16* __restrict__ dst, long n)
{
    long i0 = ((long)blockIdx.x * 256 + threadIdx.x) * 4;
    long stride = (long)gridDim.x * 1024;
    for (long i = i0; i < n; i += stride) {
        float4 v = *reinterpret_cast<const float4*>(&src[i]);
        dst[i + 0] = __float2bfloat16(v.x);
        dst[i + 1] = __float2bfloat16(v.y);
        dst[i + 2] = __float2bfloat16(v.z);
        dst[i + 3] = __float2bfloat16(v.w);
    }
}

// ---------------------------------------------------------------- im2col
__global__ __launch_bounds__(256) void im2col_kernel(
    const float* __restrict__ x_inp, __hip_bfloat16* __restrict__ patches)
{
    int bp = blockIdx.x;                 // b*196 + p
    int b = bp / NPATCH, p = bp % NPATCH;
    int py = p / 14, px = p % 14;
    const float* xb = x_inp + (long)b * 3 * 224 * 224;
    for (int e = threadIdx.x; e < 768; e += 256) {
        int c = e >> 8, i = (e >> 4) & 15, j = e & 15;
        patches[(long)bp * 768 + e] =
            __float2bfloat16(xb[((long)c * 224 + py * 16 + i) * 224 + px * 16 + j]);
    }
}

__global__ __launch_bounds__(256) void cls_token_kernel(
    const float* __restrict__ cls_emb, const float* __restrict__ pos_emb,
    float* __restrict__ x)
{
    int b = blockIdx.x;
    for (int d = threadIdx.x; d < DMODEL; d += 256)
        x[(long)b * SEQ * DMODEL + d] = cls_emb[d] + pos_emb[d];
}

// ---------------------------------------------------------------- layernorm
template<int OB>
__global__ __launch_bounds__(256) void ln_kernel(
    const float* __restrict__ in, void* __restrict__ out,
    const float* __restrict__ w, const float* __restrict__ bb,
    long in_stride, long out_stride)
{
    int row = blockIdx.x;
    const float* xr = in + (long)row * in_stride;
    int t = threadIdx.x;
    int lane = t & 63, wid = t >> 6;
    __shared__ float red[8];

    float v[3];
    float s = 0.f;
    #pragma unroll
    for (int i = 0; i < 3; ++i) { v[i] = xr[t + i * 256]; s += v[i]; }
    #pragma unroll
    for (int off = 32; off; off >>= 1) s += __shfl_xor(s, off);
    if (lane == 0) red[wid] = s;
    __syncthreads();
    float mean = (red[0] + red[1] + red[2] + red[3]) * (1.0f / DMODEL);
    float sq = 0.f;
    #pragma unroll
    for (int i = 0; i < 3; ++i) { float d = v[i] - mean; sq += d * d; }
    #pragma unroll
    for (int off = 32; off; off >>= 1) sq += __shfl_xor(sq, off);
    if (lane == 0) red[4 + wid] = sq;
    __syncthreads();
    float rstd = rsqrtf((red[4] + red[5] + red[6] + red[7]) * (1.0f / DMODEL) + 1e-5f);
    #pragma unroll
    for (int i = 0; i < 3; ++i) {
        int d = t + i * 256;
        float o = (v[i] - mean) * rstd * w[d] + bb[d];
        if (OB) ((__hip_bfloat16*)out)[(long)row * out_stride + d] = __float2bfloat16(o);
        else    ((float*)out)[(long)row * out_stride + d] = o;
    }
}

// ---------------------------------------------------------------- bf16 GEMM
// C[M,N] = A[M,K] @ W[N,K]^T (+bias / epilogue per MODE).
// Tile TM x 128 (TM = 128: 4 waves 2x2, 64x64/wave; TM = 64: 4 waves 1x4,
// 64x32/wave). BK=32, 2-buffer LDS, prefetch-next + one barrier per K-step,
// bijective XCD-chunked 1D grid swizzle. LDS chunk swizzle: c ^= (row>>1)&3.
template<int MODE, int TM>
__global__ __launch_bounds__(256) void gemm_bf16(
    const __hip_bfloat16* __restrict__ A, const __hip_bfloat16* __restrict__ W,
    const float* __restrict__ bias, float* __restrict__ Cf,
    __hip_bfloat16* __restrict__ Cb, int M, int N, int K, int NB,
    const float* __restrict__ pos)
{
    constexpr int WMF = 4;                       // M frags per wave
    constexpr int WNF = (TM == 128) ? 4 : 2;     // N frags per wave
    __shared__ short As[2][TM * 32];
    __shared__ short Bs[2][128 * 32];
    int tid = threadIdx.x, lane = tid & 63, wv = tid >> 6;

    // bijective XCD-chunked remap (m204)
    int nwg = gridDim.x, bid = blockIdx.x;
    int qq = nwg >> 3, rr = nwg & 7;
    int xcd = bid & 7, idx = bid >> 3;
    int newid = (xcd < rr ? xcd * (qq + 1) : rr * (qq + 1) + (xcd - rr) * qq) + idx;

    int bm = (newid / NB) * TM, bn = (newid % NB) * 128;

    int wm = (TM == 128) ? (wv >> 1) * 64 : 0;
    int wn = (TM == 128) ? (wv & 1) * 64 : wv * 32;
    f32x4 acc[WMF][WNF] = {};

    // staging: thread t -> storage slot (row sr = t/4, chunk sc = t%4);
    // storage chunk sc holds logical chunk sc ^ ((sr>>1)&3).
    int sr = tid >> 2, sc = tid & 3;
    int c_log = sc ^ ((sr >> 1) & 3);
    const short* Ag  = (const short*)A + (long)(bm + sr) * K + (c_log << 3);
    const short* Bg  = (const short*)W + (long)(bn + sr) * K + (c_log << 3);
    const short* Ag2 = Ag + (long)64 * K;   // TM==128 only
    const short* Bg2 = Bg + (long)64 * K;

    // MFMA fragment read offsets (elements)
    int lg = lane >> 4, lr16 = lane & 15;
    int aoff[WMF], boff[WNF];
    #pragma unroll
    for (int i = 0; i < WMF; ++i) {
        int ra = wm + i * 16 + lr16;
        aoff[i] = (ra << 5) + ((lg ^ ((ra >> 1) & 3)) << 3);
    }
    #pragma unroll
    for (int i = 0; i < WNF; ++i) {
        int rb = wn + i * 16 + lr16;
        boff[i] = (rb << 5) + ((lg ^ ((rb >> 1) & 3)) << 3);
    }

    const int KT = K >> 5;
    // prologue: stage tile 0 into buf 0
    gl2lds16(Ag, (char*)&As[0][0] + tid * 16);
    if (TM == 128) gl2lds16(Ag2, (char*)&As[0][0] + 4096 + tid * 16);
    gl2lds16(Bg,  (char*)&Bs[0][0] + tid * 16);
    gl2lds16(Bg2, (char*)&Bs[0][0] + 4096 + tid * 16);
    __syncthreads();

    int cur = 0;
    for (int t = 0; t < KT; ++t) {
        if (t + 1 < KT) {
            int ktn = (t + 1) << 5;
            char* Ad = (char*)&As[cur ^ 1][0];
            char* Bd = (char*)&Bs[cur ^ 1][0];
            gl2lds16(Ag + ktn, Ad + tid * 16);
            if (TM == 128) gl2lds16(Ag2 + ktn, Ad + 4096 + tid * 16);
            gl2lds16(Bg + ktn,  Bd + tid * 16);
            gl2lds16(Bg2 + ktn, Bd + 4096 + tid * 16);
        }
        const short* Ab = &As[cur][0];
        const short* Bb = &Bs[cur][0];
        bf16x8 af[WMF], bfr[WNF];
        #pragma unroll
        for (int i = 0; i < WMF; ++i) af[i]  = *reinterpret_cast<const bf16x8*>(&Ab[aoff[i]]);
        #pragma unroll
        for (int i = 0; i < WNF; ++i) bfr[i] = *reinterpret_cast<const bf16x8*>(&Bb[boff[i]]);
        #pragma unroll
        for (int mi = 0; mi < WMF; ++mi)
            #pragma unroll
            for (int ni = 0; ni < WNF; ++ni)
                acc[mi][ni] = __builtin_amdgcn_mfma_f32_16x16x32_bf16(
                    af[mi], bfr[ni], acc[mi][ni], 0, 0, 0);
        __syncthreads();
        cur ^= 1;
    }

    #pragma unroll
    for (int mi = 0; mi < WMF; ++mi) {
        int row0 = bm + wm + mi * 16 + (lane >> 4) * 4;
        #pragma unroll
        for (int ni = 0; ni < WNF; ++ni) {
            int col = bn + wn + ni * 16 + lr16;
            #pragma unroll
            for (int r = 0; r < 4; ++r) {
                int row = row0 + r;
                if (row >= M) continue;
                float v = acc[mi][ni][r];
                if (MODE == M_PATCH) {
                    int pb = row / 196, pp = row - pb * 196;
                    Cf[((long)(pb * SEQ + 1 + pp)) * DMODEL + col] =
                        v + pos[(long)(1 + pp) * DMODEL + col];
                } else {
                    v += bias[col];
                    long idx2 = (long)row * N + col;
                    if (MODE == M_F32)      Cf[idx2] = v;
                    else if (MODE == M_ACC) Cf[idx2] += v;
                    else if (MODE == M_QKVB) Cb[idx2] = __float2bfloat16(v);
                    else if (MODE == M_GELU)
                        Cb[idx2] = __float2bfloat16(v / (1.f + __expf(-1.702f * v)));
                }
            }
        }
    }
}

// ---------------------------------------------------------------- attention
// Fused MFMA attention: one block (256 thr, 4 waves) per (b,h).
__global__ __launch_bounds__(256) void attn_kernel(
    const __hip_bfloat16* __restrict__ qkv,  // [MPAD, 2304] bf16
    __hip_bfloat16* __restrict__ o)          // [MPAD, 768]
{
    int bh = blockIdx.x;
    int b = bh / NHEADS, h = bh % NHEADS;
    int tid = threadIdx.x, lane = tid & 63, wv = tid >> 6;
    __shared__ short Ks[SPAD * 64];
    __shared__ short Vt[64 * VSTR];
    __shared__ short Ps[4][16 * VSTR];
    const short* base = (const short*)qkv + (long)b * SEQ * 2304;

    for (int idx = tid; idx < SPAD * 8; idx += 256) {
        int r = idx >> 3, c = idx & 7;
        int4 val = make_int4(0, 0, 0, 0);
        if (r < SEQ)
            val = *reinterpret_cast<const int4*>(base + (long)r * 2304 + 768 + h * 64 + c * 8);
        *reinterpret_cast<int4*>(&Ks[r * 64 + ((c ^ (r & 7)) << 3)]) = val;
    }
    for (int idx = tid; idx < SPAD * 64; idx += 256) {
        int k = idx >> 6, d = idx & 63;
        short v = (k < SEQ) ? base[(long)k * 2304 + 1536 + h * 64 + d] : (short)0;
        Vt[d * VSTR + k] = v;
    }
    __syncthreads();

    int lg = lane >> 4, lr = lane & 15;
    short* Pw = Ps[wv];

    for (int ch = wv; ch < 13; ch += 4) {
        int q0 = ch * 16;
        const short* qp = (const short*)qkv +
            ((long)(b * SEQ) + q0 + lr) * 2304 + h * 64 + (lg << 3);
        bf16x8 qa = *reinterpret_cast<const bf16x8*>(qp);
        bf16x8 qb = *reinterpret_cast<const bf16x8*>(qp + 32);

        f32x4 sc[13];
        #pragma unroll
        for (int f = 0; f < 13; ++f) sc[f] = (f32x4){0.f, 0.f, 0.f, 0.f};
        #pragma unroll
        for (int f = 0; f < 13; ++f) {
            int row = f * 16 + lr;
            int sw = row & 7;
            const short* kr = &Ks[row * 64];
            bf16x8 k0 = *reinterpret_cast<const bf16x8*>(&kr[((lg + 0) ^ sw) << 3]);
            bf16x8 k1 = *reinterpret_cast<const bf16x8*>(&kr[((lg + 4) ^ sw) << 3]);
            sc[f] = __builtin_amdgcn_mfma_f32_16x16x32_bf16(qa, k0, sc[f], 0, 0, 0);
            sc[f] = __builtin_amdgcn_mfma_f32_16x16x32_bf16(qb, k1, sc[f], 0, 0, 0);
        }

        float mrow[4] = {-1e30f, -1e30f, -1e30f, -1e30f};
        #pragma unroll
        for (int f = 0; f < 13; ++f) {
            bool ok = f * 16 + lr < SEQ;
            #pragma unroll
            for (int r = 0; r < 4; ++r)
                if (ok) mrow[r] = fmaxf(mrow[r], sc[f][r] * 0.125f);
        }
        #pragma unroll
        for (int r = 0; r < 4; ++r)
            #pragma unroll
            for (int off = 8; off; off >>= 1)
                mrow[r] = fmaxf(mrow[r], __shfl_xor(mrow[r], off));
        float esum[4] = {0.f, 0.f, 0.f, 0.f};
        #pragma unroll
        for (int f = 0; f < 13; ++f) {
            bool ok = f * 16 + lr < SEQ;
            #pragma unroll
            for (int r = 0; r < 4; ++r) {
                float e = ok ? __expf(sc[f][r] * 0.125f - mrow[r]) : 0.f;
                sc[f][r] = e;
                esum[r] += e;
            }
        }
        #pragma unroll
        for (int r = 0; r < 4; ++r)
            #pragma unroll
            for (int off = 8; off; off >>= 1)
                esum[r] += __shfl_xor(esum[r], off);
        float inv[4];
        #pragma unroll
        for (int r = 0; r < 4; ++r) inv[r] = 1.0f / esum[r];

        #pragma unroll
        for (int f = 0; f < 13; ++f)
            #pragma unroll
            for (int r = 0; r < 4; ++r)
                Pw[(lg * 4 + r) * VSTR + f * 16 + lr] = f2b(sc[f][r] * inv[r]);

        f32x4 oa[4] = {};
        #pragma unroll
        for (int ks = 0; ks < 7; ++ks) {
            int kb = ks * 32 + (lg << 3);
            bf16x8 pa = {};
            if (kb < SPAD) pa = *reinterpret_cast<const bf16x8*>(&Pw[lr * VSTR + kb]);
            #pragma unroll
            for (int d = 0; d < 4; ++d) {
                bf16x8 vb = {};
                if (kb < SPAD)
                    vb = *reinterpret_cast<const bf16x8*>(&Vt[(d * 16 + lr) * VSTR + kb]);
                oa[d] = __builtin_amdgcn_mfma_f32_16x16x32_bf16(pa, vb, oa[d], 0, 0, 0);
            }
        }

        #pragma unroll
        for (int d = 0; d < 4; ++d)
            #pragma unroll
            for (int r = 0; r < 4; ++r) {
                int q = q0 + lg * 4 + r;
                if (q < SEQ)
                    o[((long)(b * SEQ + q)) * DMODEL + h * 64 + d * 16 + lr] =
                        __float2bfloat16(oa[d][r]);
            }
    }
}

// ---------------------------------------------------------------- final proj
__global__ __launch_bounds__(256) void proj_kernel(
    const float* __restrict__ cls_ln,  // [32,768]
    const float* __restrict__ proj,    // [768,512]
    float* __restrict__ out)           // [32,512]
{
    int idx = blockIdx.x * 256 + threadIdx.x;
    int m = idx >> 9, n = idx & 511;
    float s = 0.f;
    #pragma unroll 8
    for (int k = 0; k < 768; ++k)
        s += cls_ln[m * 768 + k] * proj[k * 512 + n];
    out[idx] = s;
}

// ---------------------------------------------------------------- launcher
extern "C" void kernel_launch(void* const* d_in, const int* in_sizes, int n_in,
                              void* d_out, int out_size, void* d_ws, size_t ws_size,
                              hipStream_t stream) {
    const float* x_inp    = (const float*)d_in[0];
    const float* conv_w   = (const float*)d_in[1];
    const float* cls_emb  = (const float*)d_in[2];
    const float* pos_emb  = (const float*)d_in[3];
    const float* ln_pre_w = (const float*)d_in[4];
    const float* ln_pre_b = (const float*)d_in[5];
    const float* ln1_w    = (const float*)d_in[6];
    const float* ln1_b    = (const float*)d_in[7];
    const float* qkv_w    = (const float*)d_in[8];
    const float* qkv_b    = (const float*)d_in[9];
    const float* out_w    = (const float*)d_in[10];
    const float* out_b    = (const float*)d_in[11];
    const float* ln2_w    = (const float*)d_in[12];
    const float* ln2_b    = (const float*)d_in[13];
    const float* fc1_w    = (const float*)d_in[14];
    const float* fc1_b    = (const float*)d_in[15];
    const float* fc2_w    = (const float*)d_in[16];
    const float* fc2_b    = (const float*)d_in[17];
    const float* ln_post_w= (const float*)d_in[18];
    const float* ln_post_b= (const float*)d_in[19];
    const float* proj     = (const float*)d_in[20];

    char* w = (char*)d_ws;
    __hip_bfloat16* wqkv = (__hip_bfloat16*)w; w += (size_t)LAYERS * 2304 * DMODEL * 2;
    __hip_bfloat16* wout = (__hip_bfloat16*)w; w += (size_t)LAYERS * DMODEL * DMODEL * 2;
    __hip_bfloat16* wfc1 = (__hip_bfloat16*)w; w += (size_t)LAYERS * FFDIM * DMODEL * 2;
    __hip_bfloat16* wfc2 = (__hip_bfloat16*)w; w += (size_t)LAYERS * DMODEL * FFDIM * 2;
    __hip_bfloat16* wconv= (__hip_bfloat16*)w; w += (size_t)DMODEL * DMODEL * 2;
    float* x             = (float*)w;          w += (size_t)MROWS * DMODEL * 4;
    __hip_bfloat16* y    = (__hip_bfloat16*)w; w += (size_t)MPAD * DMODEL * 2;
    __hip_bfloat16* qkvb = (__hip_bfloat16*)w; w += (size_t)MPAD * 2304 * 2;
    __hip_bfloat16* attno= (__hip_bfloat16*)w; w += (size_t)MPAD * DMODEL * 2;
    __hip_bfloat16* h1   = (__hip_bfloat16*)w; w += (size_t)MPAD * FFDIM * 2;
    __hip_bfloat16* patches = (__hip_bfloat16*)w; w += (size_t)NPATCH * BATCH * DMODEL * 2;
    float* clsb          = (float*)w;          w += (size_t)BATCH * DMODEL * 4;

    cvt_bf16_kernel<<<2048, 256, 0, stream>>>(qkv_w, wqkv, (long)LAYERS * 2304 * DMODEL);
    cvt_bf16_kernel<<<2048, 256, 0, stream>>>(out_w, wout, (long)LAYERS * DMODEL * DMODEL);
    cvt_bf16_kernel<<<2048, 256, 0, stream>>>(fc1_w, wfc1, (long)LAYERS * FFDIM * DMODEL);
    cvt_bf16_kernel<<<2048, 256, 0, stream>>>(fc2_w, wfc2, (long)LAYERS * DMODEL * FFDIM);
    cvt_bf16_kernel<<<512, 256, 0, stream>>>(conv_w, wconv, (long)DMODEL * DMODEL);

    im2col_kernel<<<NPATCH * BATCH, 256, 0, stream>>>(x_inp, patches);
    gemm_bf16<M_PATCH, 64><<<98 * 6, 256, 0, stream>>>(
        patches, wconv, nullptr, x, nullptr, NPATCH * BATCH, DMODEL, DMODEL, 6, pos_emb);
    cls_token_kernel<<<BATCH, 256, 0, stream>>>(cls_emb, pos_emb, x);
    ln_kernel<0><<<MROWS, 256, 0, stream>>>(x, x, ln_pre_w, ln_pre_b, DMODEL, DMODEL);

    for (int l = 0; l < LAYERS; ++l) {
        ln_kernel<1><<<MROWS, 256, 0, stream>>>(x, y, ln1_w + l * DMODEL, ln1_b + l * DMODEL,
                                                DMODEL, DMODEL);
        gemm_bf16<M_QKVB, 128><<<50 * 18, 256, 0, stream>>>(
            y, wqkv + (long)l * 2304 * DMODEL, qkv_b + (long)l * 2304, nullptr, qkvb,
            MROWS, 2304, DMODEL, 18, nullptr);
        attn_kernel<<<BATCH * NHEADS, 256, 0, stream>>>(qkvb, attno);
        gemm_bf16<M_ACC, 64><<<99 * 6, 256, 0, stream>>>(
            attno, wout + (long)l * DMODEL * DMODEL, out_b + (long)l * DMODEL, x, nullptr,
            MROWS, DMODEL, DMODEL, 6, nullptr);
        ln_kernel<1><<<MROWS, 256, 0, stream>>>(x, y, ln2_w + l * DMODEL, ln2_b + l * DMODEL,
                                                DMODEL, DMODEL);
        gemm_bf16<M_GELU, 128><<<50 * 24, 256, 0, stream>>>(
            y, wfc1 + (long)l * FFDIM * DMODEL, fc1_b + (long)l * FFDIM, nullptr, h1,
            MROWS, FFDIM, DMODEL, 24, nullptr);
        gemm_bf16<M_ACC, 64><<<99 * 6, 256, 0, stream>>>(
            h1, wfc2 + (long)l * DMODEL * FFDIM, fc2_b + (long)l * DMODEL, x, nullptr,
            MROWS, DMODEL, FFDIM, 6, nullptr);
    }

    ln_kernel<0><<<BATCH, 256, 0, stream>>>(x, clsb, ln_post_w, ln_post_b,
                                            (long)SEQ * DMODEL, DMODEL);
    proj_kernel<<<(BATCH * OUTD) / 256, 256, 0, stream>>>(clsb, proj, (float*)d_out);
}

// Round 8
// 3438.004 us; speedup vs baseline: 1.2600x; 1.0317x over previous
//
#include <hip/hip_runtime.h>
#include <hip/hip_bf16.h>

// CLIP ViT-B/16 visual forward — Round 7: uniform 64x128 tile, BK=64 GEMM
// (half the barrier drains of BK=32), 8-chunk XOR swizzle, 2-buffer LDS,
// XCD-chunked grid swizzle. Attention/LN unchanged.

#define LAYERS 12
#define DMODEL 768
#define NHEADS 12
#define DHEAD  64
#define FFDIM  3072
#define BATCH  32
#define SEQ    197
#define NPATCH 196
#define OUTD   512
#define MROWS  (BATCH * SEQ)   // 6304
#define MPAD   6400            // 50 * 128
#define SPAD   208             // 13 * 16 (padded seq)
#define VSTR   208

typedef __attribute__((ext_vector_type(4))) float f32x4;
typedef __attribute__((ext_vector_type(8))) short bf16x8;

enum { M_F32 = 0, M_ACC = 1, M_GELU = 2, M_PATCH = 3, M_QKVB = 4 };

__device__ __forceinline__ float b2f(short s) {
    unsigned u = ((unsigned)(unsigned short)s) << 16;
    return __builtin_bit_cast(float, u);
}
__device__ __forceinline__ short f2b(float f) {
    __hip_bfloat16 h = __float2bfloat16(f);
    return __builtin_bit_cast(short, h);
}

__device__ __forceinline__ void gl2lds16(const void* g, void* l) {
    __builtin_amdgcn_global_load_lds(
        (const __attribute__((address_space(1))) void*)g,
        (__attribute__((address_space(3))) void*)l, 16, 0, 0);
}

// ---------------------------------------------------------------- weight cvt
__global__ __launch_bounds__(256) void cvt_bf16_kernel(
    const float* __restrict__ src, __hip_bfloat16* __restrict__ dst, long n)
{
    long i0 = ((long)blockIdx.x * 256 + threadIdx.x) * 4;
    long stride = (long)gridDim.x * 1024;
    for (long i = i0; i < n; i += stride) {
        float4 v = *reinterpret_cast<const float4*>(&src[i]);
        dst[i + 0] = __float2bfloat16(v.x);
        dst[i + 1] = __float2bfloat16(v.y);
        dst[i + 2] = __float2bfloat16(v.z);
        dst[i + 3] = __float2bfloat16(v.w);
    }
}

// ---------------------------------------------------------------- im2col
__global__ __launch_bounds__(256) void im2col_kernel(
    const float* __restrict__ x_inp, __hip_bfloat16* __restrict__ patches)
{
    int bp = blockIdx.x;                 // b*196 + p
    int b = bp / NPATCH, p = bp % NPATCH;
    int py = p / 14, px = p % 14;
    const float* xb = x_inp + (long)b * 3 * 224 * 224;
    for (int e = threadIdx.x; e < 768; e += 256) {
        int c = e >> 8, i = (e >> 4) & 15, j = e & 15;
        patches[(long)bp * 768 + e] =
            __float2bfloat16(xb[((long)c * 224 + py * 16 + i) * 224 + px * 16 + j]);
    }
}

__global__ __launch_bounds__(256) void cls_token_kernel(
    const float* __restrict__ cls_emb, const float* __restrict__ pos_emb,
    float* __restrict__ x)
{
    int b = blockIdx.x;
    for (int d = threadIdx.x; d < DMODEL; d += 256)
        x[(long)b * SEQ * DMODEL + d] = cls_emb[d] + pos_emb[d];
}

// ---------------------------------------------------------------- layernorm
template<int OB>
__global__ __launch_bounds__(256) void ln_kernel(
    const float* __restrict__ in, void* __restrict__ out,
    const float* __restrict__ w, const float* __restrict__ bb,
    long in_stride, long out_stride)
{
    int row = blockIdx.x;
    const float* xr = in + (long)row * in_stride;
    int t = threadIdx.x;
    int lane = t & 63, wid = t >> 6;
    __shared__ float red[8];

    float v[3];
    float s = 0.f;
    #pragma unroll
    for (int i = 0; i < 3; ++i) { v[i] = xr[t + i * 256]; s += v[i]; }
    #pragma unroll
    for (int off = 32; off; off >>= 1) s += __shfl_xor(s, off);
    if (lane == 0) red[wid] = s;
    __syncthreads();
    float mean = (red[0] + red[1] + red[2] + red[3]) * (1.0f / DMODEL);
    float sq = 0.f;
    #pragma unroll
    for (int i = 0; i < 3; ++i) { float d = v[i] - mean; sq += d * d; }
    #pragma unroll
    for (int off = 32; off; off >>= 1) sq += __shfl_xor(sq, off);
    if (lane == 0) red[4 + wid] = sq;
    __syncthreads();
    float rstd = rsqrtf((red[4] + red[5] + red[6] + red[7]) * (1.0f / DMODEL) + 1e-5f);
    #pragma unroll
    for (int i = 0; i < 3; ++i) {
        int d = t + i * 256;
        float o = (v[i] - mean) * rstd * w[d] + bb[d];
        if (OB) ((__hip_bfloat16*)out)[(long)row * out_stride + d] = __float2bfloat16(o);
        else    ((float*)out)[(long)row * out_stride + d] = o;
    }
}

// ---------------------------------------------------------------- bf16 GEMM
// C[M,N] = A[M,K] @ W[N,K]^T (+bias / epilogue per MODE).
// Tile 64x128, BK=64, 2-buffer LDS (48KB -> 3 blocks/CU), one barrier per
// K-step (half as many as BK=32), bijective XCD-chunked 1D grid swizzle.
// LDS layout: row stride 64 elems (128B); chunk (8 elems) c stored at
// slot c ^ (row&7) -> 2-way max on both staging and frag ds_read_b128.
template<int MODE>
__global__ __launch_bounds__(256) void gemm_bf16(
    const __hip_bfloat16* __restrict__ A, const __hip_bfloat16* __restrict__ W,
    const float* __restrict__ bias, float* __restrict__ Cf,
    __hip_bfloat16* __restrict__ Cb, int M, int N, int K, int NB,
    const float* __restrict__ pos)
{
    __shared__ short As[2][64 * 64];
    __shared__ short Bs[2][128 * 64];
    int tid = threadIdx.x, lane = tid & 63, wv = tid >> 6;

    // bijective XCD-chunked remap (m204)
    int nwg = gridDim.x, bid = blockIdx.x;
    int qq = nwg >> 3, rr = nwg & 7;
    int xcd = bid & 7, idx = bid >> 3;
    int newid = (xcd < rr ? xcd * (qq + 1) : rr * (qq + 1) + (xcd - rr) * qq) + idx;

    int bm = (newid / NB) * 64, bn = (newid % NB) * 128;
    int wn = wv * 32;
    f32x4 acc[4][2] = {};

    // staging: thread t -> (row sr = t/8, chunk sc = t%8) within a 32-row pass;
    // storage chunk sc holds logical chunk sc ^ (sr&7); rows sr+32k keep sr&7.
    int sr = tid >> 3, sc = tid & 7;
    int c_log = sc ^ (sr & 7);
    const short* Ag = (const short*)A + (long)(bm + sr) * K + (c_log << 3);
    const short* Bg = (const short*)W + (long)(bn + sr) * K + (c_log << 3);
    const long K32 = (long)32 * K;

    // MFMA fragment read offsets (elements), per ksub s
    int lg = lane >> 4, lr16 = lane & 15;
    int aoff[2][4], boff[2][2];
    #pragma unroll
    for (int s = 0; s < 2; ++s) {
        #pragma unroll
        for (int i = 0; i < 4; ++i) {
            int ra = i * 16 + lr16;
            aoff[s][i] = (ra << 6) + ((((s << 2) | lg) ^ (ra & 7)) << 3);
        }
        #pragma unroll
        for (int j = 0; j < 2; ++j) {
            int rb = wn + j * 16 + lr16;
            boff[s][j] = (rb << 6) + ((((s << 2) | lg) ^ (rb & 7)) << 3);
        }
    }

    const int KT = K >> 6;
    // prologue: stage tile 0 into buf 0 (A: 2 passes, B: 4 passes)
    {
        char* Ad = (char*)&As[0][0]; char* Bd = (char*)&Bs[0][0];
        gl2lds16(Ag,           Ad + tid * 16);
        gl2lds16(Ag + K32,     Ad + 4096 + tid * 16);
        gl2lds16(Bg,           Bd + tid * 16);
        gl2lds16(Bg + K32,     Bd + 4096 + tid * 16);
        gl2lds16(Bg + 2 * K32, Bd + 8192 + tid * 16);
        gl2lds16(Bg + 3 * K32, Bd + 12288 + tid * 16);
    }
    __syncthreads();

    int cur = 0;
    for (int t = 0; t < KT; ++t) {
        if (t + 1 < KT) {
            int ktn = (t + 1) << 6;
            char* Ad = (char*)&As[cur ^ 1][0];
            char* Bd = (char*)&Bs[cur ^ 1][0];
            gl2lds16(Ag + ktn,           Ad + tid * 16);
            gl2lds16(Ag + K32 + ktn,     Ad + 4096 + tid * 16);
            gl2lds16(Bg + ktn,           Bd + tid * 16);
            gl2lds16(Bg + K32 + ktn,     Bd + 4096 + tid * 16);
            gl2lds16(Bg + 2 * K32 + ktn, Bd + 8192 + tid * 16);
            gl2lds16(Bg + 3 * K32 + ktn, Bd + 12288 + tid * 16);
        }
        const short* Ab = &As[cur][0];
        const short* Bb = &Bs[cur][0];
        #pragma unroll
        for (int s = 0; s < 2; ++s) {
            bf16x8 af[4], bfr[2];
            #pragma unroll
            for (int i = 0; i < 4; ++i)
                af[i] = *reinterpret_cast<const bf16x8*>(&Ab[aoff[s][i]]);
            #pragma unroll
            for (int j = 0; j < 2; ++j)
                bfr[j] = *reinterpret_cast<const bf16x8*>(&Bb[boff[s][j]]);
            #pragma unroll
            for (int mi = 0; mi < 4; ++mi)
                #pragma unroll
                for (int ni = 0; ni < 2; ++ni)
                    acc[mi][ni] = __builtin_amdgcn_mfma_f32_16x16x32_bf16(
                        af[mi], bfr[ni], acc[mi][ni], 0, 0, 0);
        }
        __syncthreads();
        cur ^= 1;
    }

    #pragma unroll
    for (int mi = 0; mi < 4; ++mi) {
        int row0 = bm + mi * 16 + (lane >> 4) * 4;
        #pragma unroll
        for (int ni = 0; ni < 2; ++ni) {
            int col = bn + wn + ni * 16 + lr16;
            #pragma unroll
            for (int r = 0; r < 4; ++r) {
                int row = row0 + r;
                if (row >= M) continue;
                float v = acc[mi][ni][r];
                if (MODE == M_PATCH) {
                    int pb = row / 196, pp = row - pb * 196;
                    Cf[((long)(pb * SEQ + 1 + pp)) * DMODEL + col] =
                        v + pos[(long)(1 + pp) * DMODEL + col];
                } else {
                    v += bias[col];
                    long idx2 = (long)row * N + col;
                    if (MODE == M_F32)      Cf[idx2] = v;
                    else if (MODE == M_ACC) Cf[idx2] += v;
                    else if (MODE == M_QKVB) Cb[idx2] = __float2bfloat16(v);
                    else if (MODE == M_GELU)
                        Cb[idx2] = __float2bfloat16(v / (1.f + __expf(-1.702f * v)));
                }
            }
        }
    }
}

// ---------------------------------------------------------------- attention
// Fused MFMA attention: one block (256 thr, 4 waves) per (b,h).
__global__ __launch_bounds__(256) void attn_kernel(
    const __hip_bfloat16* __restrict__ qkv,  // [MPAD, 2304] bf16
    __hip_bfloat16* __restrict__ o)          // [MPAD, 768]
{
    int bh = blockIdx.x;
    int b = bh / NHEADS, h = bh % NHEADS;
    int tid = threadIdx.x, lane = tid & 63, wv = tid >> 6;
    __shared__ short Ks[SPAD * 64];
    __shared__ short Vt[64 * VSTR];
    __shared__ short Ps[4][16 * VSTR];
    const short* base = (const short*)qkv + (long)b * SEQ * 2304;

    for (int idx = tid; idx < SPAD * 8; idx += 256) {
        int r = idx >> 3, c = idx & 7;
        int4 val = make_int4(0, 0, 0, 0);
        if (r < SEQ)
            val = *reinterpret_cast<const int4*>(base + (long)r * 2304 + 768 + h * 64 + c * 8);
        *reinterpret_cast<int4*>(&Ks[r * 64 + ((c ^ (r & 7)) << 3)]) = val;
    }
    for (int idx = tid; idx < SPAD * 64; idx += 256) {
        int k = idx >> 6, d = idx & 63;
        short v = (k < SEQ) ? base[(long)k * 2304 + 1536 + h * 64 + d] : (short)0;
        Vt[d * VSTR + k] = v;
    }
    __syncthreads();

    int lg = lane >> 4, lr = lane & 15;
    short* Pw = Ps[wv];

    for (int ch = wv; ch < 13; ch += 4) {
        int q0 = ch * 16;
        const short* qp = (const short*)qkv +
            ((long)(b * SEQ) + q0 + lr) * 2304 + h * 64 + (lg << 3);
        bf16x8 qa = *reinterpret_cast<const bf16x8*>(qp);
        bf16x8 qb = *reinterpret_cast<const bf16x8*>(qp + 32);

        f32x4 sc[13];
        #pragma unroll
        for (int f = 0; f < 13; ++f) sc[f] = (f32x4){0.f, 0.f, 0.f, 0.f};
        #pragma unroll
        for (int f = 0; f < 13; ++f) {
            int row = f * 16 + lr;
            int sw = row & 7;
            const short* kr = &Ks[row * 64];
            bf16x8 k0 = *reinterpret_cast<const bf16x8*>(&kr[((lg + 0) ^ sw) << 3]);
            bf16x8 k1 = *reinterpret_cast<const bf16x8*>(&kr[((lg + 4) ^ sw) << 3]);
            sc[f] = __builtin_amdgcn_mfma_f32_16x16x32_bf16(qa, k0, sc[f], 0, 0, 0);
            sc[f] = __builtin_amdgcn_mfma_f32_16x16x32_bf16(qb, k1, sc[f], 0, 0, 0);
        }

        float mrow[4] = {-1e30f, -1e30f, -1e30f, -1e30f};
        #pragma unroll
        for (int f = 0; f < 13; ++f) {
            bool ok = f * 16 + lr < SEQ;
            #pragma unroll
            for (int r = 0; r < 4; ++r)
                if (ok) mrow[r] = fmaxf(mrow[r], sc[f][r] * 0.125f);
        }
        #pragma unroll
        for (int r = 0; r < 4; ++r)
            #pragma unroll
            for (int off = 8; off; off >>= 1)
                mrow[r] = fmaxf(mrow[r], __shfl_xor(mrow[r], off));
        float esum[4] = {0.f, 0.f, 0.f, 0.f};
        #pragma unroll
        for (int f = 0; f < 13; ++f) {
            bool ok = f * 16 + lr < SEQ;
            #pragma unroll
            for (int r = 0; r < 4; ++r) {
                float e = ok ? __expf(sc[f][r] * 0.125f - mrow[r]) : 0.f;
                sc[f][r] = e;
                esum[r] += e;
            }
        }
        #pragma unroll
        for (int r = 0; r < 4; ++r)
            #pragma unroll
            for (int off = 8; off; off >>= 1)
                esum[r] += __shfl_xor(esum[r], off);
        float inv[4];
        #pragma unroll
        for (int r = 0; r < 4; ++r) inv[r] = 1.0f / esum[r];

        #pragma unroll
        for (int f = 0; f < 13; ++f)
            #pragma unroll
            for (int r = 0; r < 4; ++r)
                Pw[(lg * 4 + r) * VSTR + f * 16 + lr] = f2b(sc[f][r] * inv[r]);

        f32x4 oa[4] = {};
        #pragma unroll
        for (int ks = 0; ks < 7; ++ks) {
            int kb = ks * 32 + (lg << 3);
            bf16x8 pa = {};
            if (kb < SPAD) pa = *reinterpret_cast<const bf16x8*>(&Pw[lr * VSTR + kb]);
            #pragma unroll
            for (int d = 0; d < 4; ++d) {
                bf16x8 vb = {};
                if (kb < SPAD)
                    vb = *reinterpret_cast<const bf16x8*>(&Vt[(d * 16 + lr) * VSTR + kb]);
                oa[d] = __builtin_amdgcn_mfma_f32_16x16x32_bf16(pa, vb, oa[d], 0, 0, 0);
            }
        }

        #pragma unroll
        for (int d = 0; d < 4; ++d)
            #pragma unroll
            for (int r = 0; r < 4; ++r) {
                int q = q0 + lg * 4 + r;
                if (q < SEQ)
                    o[((long)(b * SEQ + q)) * DMODEL + h * 64 + d * 16 + lr] =
                        __float2bfloat16(oa[d][r]);
            }
    }
}

// ---------------------------------------------------------------- final proj
__global__ __launch_bounds__(256) void proj_kernel(
    const float* __restrict__ cls_ln,  // [32,768]
    const float* __restrict__ proj,    // [768,512]
    float* __restrict__ out)           // [32,512]
{
    int idx = blockIdx.x * 256 + threadIdx.x;
    int m = idx >> 9, n = idx & 511;
    float s = 0.f;
    #pragma unroll 8
    for (int k = 0; k < 768; ++k)
        s += cls_ln[m * 768 + k] * proj[k * 512 + n];
    out[idx] = s;
}

// ---------------------------------------------------------------- launcher
extern "C" void kernel_launch(void* const* d_in, const int* in_sizes, int n_in,
                              void* d_out, int out_size, void* d_ws, size_t ws_size,
                              hipStream_t stream) {
    const float* x_inp    = (const float*)d_in[0];
    const float* conv_w   = (const float*)d_in[1];
    const float* cls_emb  = (const float*)d_in[2];
    const float* pos_emb  = (const float*)d_in[3];
    const float* ln_pre_w = (const float*)d_in[4];
    const float* ln_pre_b = (const float*)d_in[5];
    const float* ln1_w    = (const float*)d_in[6];
    const float* ln1_b    = (const float*)d_in[7];
    const float* qkv_w    = (const float*)d_in[8];
    const float* qkv_b    = (const float*)d_in[9];
    const float* out_w    = (const float*)d_in[10];
    const float* out_b    = (const float*)d_in[11];
    const float* ln2_w    = (const float*)d_in[12];
    const float* ln2_b    = (const float*)d_in[13];
    const float* fc1_w    = (const float*)d_in[14];
    const float* fc1_b    = (const float*)d_in[15];
    const float* fc2_w    = (const float*)d_in[16];
    const float* fc2_b    = (const float*)d_in[17];
    const float* ln_post_w= (const float*)d_in[18];
    const float* ln_post_b= (const float*)d_in[19];
    const float* proj     = (const float*)d_in[20];

    char* w = (char*)d_ws;
    __hip_bfloat16* wqkv = (__hip_bfloat16*)w; w += (size_t)LAYERS * 2304 * DMODEL * 2;
    __hip_bfloat16* wout = (__hip_bfloat16*)w; w += (size_t)LAYERS * DMODEL * DMODEL * 2;
    __hip_bfloat16* wfc1 = (__hip_bfloat16*)w; w += (size_t)LAYERS * FFDIM * DMODEL * 2;
    __hip_bfloat16* wfc2 = (__hip_bfloat16*)w; w += (size_t)LAYERS * DMODEL * FFDIM * 2;
    __hip_bfloat16* wconv= (__hip_bfloat16*)w; w += (size_t)DMODEL * DMODEL * 2;
    float* x             = (float*)w;          w += (size_t)MROWS * DMODEL * 4;
    __hip_bfloat16* y    = (__hip_bfloat16*)w; w += (size_t)MPAD * DMODEL * 2;
    __hip_bfloat16* qkvb = (__hip_bfloat16*)w; w += (size_t)MPAD * 2304 * 2;
    __hip_bfloat16* attno= (__hip_bfloat16*)w; w += (size_t)MPAD * DMODEL * 2;
    __hip_bfloat16* h1   = (__hip_bfloat16*)w; w += (size_t)MPAD * FFDIM * 2;
    __hip_bfloat16* patches = (__hip_bfloat16*)w; w += (size_t)NPATCH * BATCH * DMODEL * 2;
    float* clsb          = (float*)w;          w += (size_t)BATCH * DMODEL * 4;

    cvt_bf16_kernel<<<2048, 256, 0, stream>>>(qkv_w, wqkv, (long)LAYERS * 2304 * DMODEL);
    cvt_bf16_kernel<<<2048, 256, 0, stream>>>(out_w, wout, (long)LAYERS * DMODEL * DMODEL);
    cvt_bf16_kernel<<<2048, 256, 0, stream>>>(fc1_w, wfc1, (long)LAYERS * FFDIM * DMODEL);
    cvt_bf16_kernel<<<2048, 256, 0, stream>>>(fc2_w, wfc2, (long)LAYERS * DMODEL * FFDIM);
    cvt_bf16_kernel<<<512, 256, 0, stream>>>(conv_w, wconv, (long)DMODEL * DMODEL);

    im2col_kernel<<<NPATCH * BATCH, 256, 0, stream>>>(x_inp, patches);
    gemm_bf16<M_PATCH><<<98 * 6, 256, 0, stream>>>(
        patches, wconv, nullptr, x, nullptr, NPATCH * BATCH, DMODEL, DMODEL, 6, pos_emb);
    cls_token_kernel<<<BATCH, 256, 0, stream>>>(cls_emb, pos_emb, x);
    ln_kernel<0><<<MROWS, 256, 0, stream>>>(x, x, ln_pre_w, ln_pre_b, DMODEL, DMODEL);

    for (int l = 0; l < LAYERS; ++l) {
        ln_kernel<1><<<MROWS, 256, 0, stream>>>(x, y, ln1_w + l * DMODEL, ln1_b + l * DMODEL,
                                                DMODEL, DMODEL);
        gemm_bf16<M_QKVB><<<99 * 18, 256, 0, stream>>>(
            y, wqkv + (long)l * 2304 * DMODEL, qkv_b + (long)l * 2304, nullptr, qkvb,
            MROWS, 2304, DMODEL, 18, nullptr);
        attn_kernel<<<BATCH * NHEADS, 256, 0, stream>>>(qkvb, attno);
        gemm_bf16<M_ACC><<<99 * 6, 256, 0, stream>>>(
            attno, wout + (long)l * DMODEL * DMODEL, out_b + (long)l * DMODEL, x, nullptr,
            MROWS, DMODEL, DMODEL, 6, nullptr);
        ln_kernel<1><<<MROWS, 256, 0, stream>>>(x, y, ln2_w + l * DMODEL, ln2_b + l * DMODEL,
                                                DMODEL, DMODEL);
        gemm_bf16<M_GELU><<<99 * 24, 256, 0, stream>>>(
            y, wfc1 + (long)l * FFDIM * DMODEL, fc1_b + (long)l * FFDIM, nullptr, h1,
            MROWS, FFDIM, DMODEL, 24, nullptr);
        gemm_bf16<M_ACC><<<99 * 6, 256, 0, stream>>>(
            h1, wfc2 + (long)l * DMODEL * FFDIM, fc2_b + (long)l * DMODEL, x, nullptr,
            MROWS, DMODEL, FFDIM, 6, nullptr);
    }

    ln_kernel<0><<<BATCH, 256, 0, stream>>>(x, clsb, ln_post_w, ln_post_b,
                                            (long)SEQ * DMODEL, DMODEL);
    proj_kernel<<<(BATCH * OUTD) / 256, 256, 0, stream>>>(clsb, proj, (float*)d_out);
}